// Round 1
// baseline (113.360 us; speedup 1.0000x reference)
//
#include <hip/hip_runtime.h>

#define BLK 256
#define WPT 10                  // float4 per lane -> 2560-element capacity per WAVE
#define WCAP (WPT * 64 * 4)     // 2560 (group mean 2048, max ~2250 for this input)
#define CCAP 320                // candidate buffer per wave: c<=64 exact; <=CCAP wave-Michelot; else register Michelot

// ---------- wave-local reductions (64-lane) ----------

__device__ __forceinline__ float wave_max(float v) {
#pragma unroll
  for (int o = 32; o; o >>= 1) v = fmaxf(v, __shfl_xor(v, o));
  return v;
}
__device__ __forceinline__ float wave_sum(float v) {
#pragma unroll
  for (int o = 32; o; o >>= 1) v += __shfl_xor(v, o);
  return v;
}
__device__ __forceinline__ int wave_sum_i(int v) {
#pragma unroll
  for (int o = 32; o; o >>= 1) v += __shfl_xor(v, o);
  return v;
}

// ---------- kernel 1: boundary detect -> starts[0..B], int4-vectorized ----------
// Coalesced stream of the whole batch array. Measured better than the
// 65-ary wave-search variant (R5 112.4 vs R7/R8/R9 114-118). Unchanged this
// round to isolate the kernel-2 A/B.

extern "C" __global__ void __launch_bounds__(256)
build_starts(const int* __restrict__ batch, int* __restrict__ starts,
             const int* __restrict__ pB, int N) {
  const int B = *pB;
  const long long tid = (long long)blockIdx.x * 256 + threadIdx.x;
  const long long i0 = tid * 8;
  if (i0 >= N) return;
  int v[8];
  if (i0 + 8 <= N) {
    const int4 a = *(const int4*)(batch + i0);
    const int4 b = *(const int4*)(batch + i0 + 4);
    v[0] = a.x; v[1] = a.y; v[2] = a.z; v[3] = a.w;
    v[4] = b.x; v[5] = b.y; v[6] = b.z; v[7] = b.w;
  } else {
#pragma unroll
    for (int t = 0; t < 8; ++t) v[t] = (i0 + t < N) ? batch[i0 + t] : 0;
  }
  int prev = (i0 == 0) ? -1 : batch[i0 - 1];   // same cacheline as neighbor: L1 hit
#pragma unroll
  for (int t = 0; t < 8; ++t) {
    if (i0 + t >= N) break;
    const int cur = v[t];
    for (int g = prev + 1; g <= cur; ++g) starts[g] = (int)(i0 + t);
    prev = cur;
  }
  if (i0 + 8 >= N) {
    for (int g = prev + 1; g <= B; ++g) starts[g] = N;
  }
}

// ---------- kernel 2: one WAVE per group — zero barriers, zero atomics ----------
// R(prev) block-per-group had 3 __syncthreads + wave-0-only solve + LDS atomics;
// total traffic (~100 MB) implies ~16 us roofline vs 112 us measured, i.e.
// latency/serialization-bound. One 64-lane wave holds an entire group
// (<=2560 elems) in 10 float4 registers; ballot-compaction uses a uniform
// register counter (ballot is wave-uniform => no atomicAdd), every wave solves
// its own group (no idle lanes at a barrier), all reductions are shuffles.
// 4096 groups = 4096 waves = 1024 blocks -> single occupancy round.

extern "C" __global__ void __launch_bounds__(BLK)
sparsemax_groups(const float* __restrict__ x, const int* __restrict__ starts,
                 const int* __restrict__ pB, float* __restrict__ out, int N) {
  __shared__ float cand[4][CCAP];     // per-wave candidate buffers
  __shared__ float sorted_[4][64];    // per-wave rank-scatter scratch
  const int tid  = threadIdx.x;
  const int lane = tid & 63;
  const int w    = tid >> 6;
  const int B = *pB;

  for (int g = blockIdx.x * 4 + w; g < B; g += gridDim.x * 4) {
    const int s = starts[g];
    const int e = starts[g + 1];
    const int n = e - s;
    if (n <= 0) continue;
    const int a0 = s & ~3;               // 16B-aligned load base

    if (e - a0 <= WCAP) {
      // ---- phase 1: aligned float4 global -> registers, fused max ----
      float4 r[WPT];
      float lmax = -INFINITY;
#pragma unroll
      for (int j = 0; j < WPT; ++j) {
        const int idx = a0 + (j * 64 + lane) * 4;
        float4 v = make_float4(-INFINITY, -INFINITY, -INFINITY, -INFINITY);
        if (idx < e) {
          if (idx + 4 <= N) {
            v = *(const float4*)(x + idx);
          } else {                        // buffer tail (last group only)
            if (idx + 0 < N) v.x = x[idx + 0];
            if (idx + 1 < N) v.y = x[idx + 1];
            if (idx + 2 < N) v.z = x[idx + 2];
            if (idx + 3 < N) v.w = x[idx + 3];
          }
          if (idx + 0 < s || idx + 0 >= e) v.x = -INFINITY;  // mask other groups
          if (idx + 1 < s || idx + 1 >= e) v.y = -INFINITY;
          if (idx + 2 < s || idx + 2 >= e) v.z = -INFINITY;
          if (idx + 3 < s || idx + 3 >= e) v.w = -INFINITY;
        }
        r[j] = v;
        lmax = fmaxf(lmax, fmaxf(fmaxf(v.x, v.y), fmaxf(v.z, v.w)));
      }
      const float gmax = wave_max(lmax);
      const float thr = gmax - 1.0f;     // tau >= -1 bound (outputs sum to 1)

      // ---- phase 2: ballot compaction; cnt is wave-uniform in a register ----
      int cnt = 0;
      float wsum = 0.0f;                 // this lane's candidate sum (shifted)
#pragma unroll
      for (int j = 0; j < WPT; ++j) {
        const float vv[4] = {r[j].x, r[j].y, r[j].z, r[j].w};
#pragma unroll
        for (int t = 0; t < 4; ++t) {
          const bool p = vv[t] > thr;
          const unsigned long long bal = __ballot(p);
          if (bal) {                     // wave-uniform branch (s_cbranch)
            if (p) {
              const int off = cnt + __popcll(bal & ((1ull << lane) - 1ull));
              if (off < CCAP) cand[w][off] = vv[t];
              wsum += vv[t] - gmax;
            }
            cnt += __popcll(bal);        // ballot is uniform -> no atomic needed
          }
        }
      }
      wsum = wave_sum(wsum);
      const int c = cnt;                 // >= 1 (max element always passes)

      float tau;
      if (c <= 64) {
        // exact rank-sort + shfl prefix-scan + ballot solve (every wave)
        const float v = (lane < c) ? cand[w][lane] - gmax : 0.0f;
        int rank = 0;
        for (int q = 0; q < c; ++q) {
          const float t = cand[w][q] - gmax;
          rank += (t > v) || (t == v && q < lane);   // unique ranks
        }
        if (lane < c) sorted_[w][rank] = v;          // sorted_[w][0] == 0
        const float sv = (lane < c) ? sorted_[w][lane] : 0.0f;  // same-wave DS: in-order
        float cs = sv;
#pragma unroll
        for (int o = 1; o < 64; o <<= 1) {           // inclusive prefix scan
          const float t2 = __shfl_up(cs, o);
          if (lane >= o) cs += t2;
        }
        const int flag = (lane < c) && (sv * (float)(lane + 1) > cs - 1.0f);
        const unsigned long long bal2 = __ballot(flag);  // lane 0 always true
        const int k = 63 - __clzll(bal2);                // support size - 1
        const float csk = __shfl(cs, k);
        tau = (csk - 1.0f) / (float)(k + 1);
      } else if (c <= CCAP) {
        // wave Michelot over LDS candidates
        tau = (wsum - 1.0f) / (float)c;
        int cnt2 = c;
        for (int it = 0; it < 64; ++it) {
          float s2 = 0.0f; int c2 = 0;
          for (int q = lane; q < c; q += 64) {
            const float vs = cand[w][q] - gmax;
            if (vs > tau) { s2 += vs; c2++; }
          }
          s2 = wave_sum(s2); c2 = wave_sum_i(c2);
          if (c2 == cnt2 || c2 == 0) break;
          tau = (s2 - 1.0f) / (float)c2; cnt2 = c2;
        }
      } else {
        // pathological path: Michelot on registers, wave-local (-inf never passes)
        tau = (wsum - 1.0f) / (float)c;
        int cnt2 = c;
        for (int it = 0; it < 64; ++it) {
          float s2 = 0.0f; int c2 = 0;
#pragma unroll
          for (int j = 0; j < WPT; ++j) {
            const float vv[4] = {r[j].x, r[j].y, r[j].z, r[j].w};
#pragma unroll
            for (int t = 0; t < 4; ++t) {
              const float vs = vv[t] - gmax;
              if (vs > tau) { s2 += vs; c2++; }
            }
          }
          s2 = wave_sum(s2); c2 = wave_sum_i(c2);
          if (c2 == cnt2 || c2 == 0) break;
          tau = (s2 - 1.0f) / (float)c2; cnt2 = c2;
        }
      }

      const float sub = tau + gmax;      // unshifted threshold

      // ---- phase 3: store (vector interior, scalar boundary quads) ----
#pragma unroll
      for (int j = 0; j < WPT; ++j) {
        const int idx = a0 + (j * 64 + lane) * 4;
        if (idx >= e) continue;
        if (idx >= s && idx + 4 <= e) {
          float4 o4;
          o4.x = fmaxf(r[j].x - sub, 0.0f);
          o4.y = fmaxf(r[j].y - sub, 0.0f);
          o4.z = fmaxf(r[j].z - sub, 0.0f);
          o4.w = fmaxf(r[j].w - sub, 0.0f);
          *(float4*)(out + idx) = o4;
        } else {
          const float vv[4] = {r[j].x, r[j].y, r[j].z, r[j].w};
#pragma unroll
          for (int t = 0; t < 4; ++t) {
            const int p2 = idx + t;
            if (p2 >= s && p2 < e) out[p2] = fmaxf(vv[t] - sub, 0.0f);
          }
        }
      }
    } else {
      // ---- n > capacity fallback: wave-strided global Michelot (no barriers) ----
      float gmax = -INFINITY;
      for (int i = s + lane; i < e; i += 64) gmax = fmaxf(gmax, x[i]);
      gmax = wave_max(gmax);
      float bs = 0.0f; int bc = 0;
      for (int i = s + lane; i < e; i += 64) {
        const float vs = x[i] - gmax;
        if (vs > -1.0f) { bs += vs; bc++; }
      }
      bs = wave_sum(bs); bc = wave_sum_i(bc);
      float tau = (bs - 1.0f) / (float)bc;
      int cntS = bc;
      for (int it = 0; it < 64; ++it) {
        float s2 = 0.0f; int c2 = 0;
        for (int i = s + lane; i < e; i += 64) {
          const float vs = x[i] - gmax;
          if (vs > tau) { s2 += vs; c2++; }
        }
        s2 = wave_sum(s2); c2 = wave_sum_i(c2);
        if (c2 == cntS || c2 == 0) break;
        tau = (s2 - 1.0f) / (float)c2; cntS = c2;
      }
      const float sub = tau + gmax;
      for (int i = s + lane; i < e; i += 64) out[i] = fmaxf(x[i] - sub, 0.0f);
    }
  }
}

extern "C" void kernel_launch(void* const* d_in, const int* in_sizes, int n_in,
                              void* d_out, int out_size, void* d_ws, size_t ws_size,
                              hipStream_t stream) {
  const float* x     = (const float*)d_in[0];
  const int*   batch = (const int*)d_in[1];   // int32 on device (JAX x64 disabled)
  const int*   pB    = (const int*)d_in[2];
  float*       out   = (float*)d_out;
  const int N = in_sizes[0];

  int* starts = (int*)d_ws;                    // 4*(B+1) bytes of scratch

  const int g1 = (N + 2047) / 2048;            // 8 elems/thread, 256 threads
  build_starts<<<dim3(g1), dim3(256), 0, stream>>>(batch, starts, pB, N);
  // one wave per group: 1024 blocks x 4 waves = 4096 waves; grid-strides if B > 16384
  sparsemax_groups<<<dim3(1024), dim3(BLK), 0, stream>>>(x, starts, pB, out, N);
}